// Round 5
// baseline (26745.099 us; speedup 1.0000x reference)
//
#include <hip/hip_runtime.h>
#include <hip/hip_fp16.h>
#include <math.h>

// ESN recurrence, round 5.
// R4 post-timing divergence root-cause candidate: R4's poll required all 4
// u64s to tag-match in the SAME read round (no lock-in). A transient reader
// stall letting producers lap by DSLOT tags destroys an un-captured tag ->
// that poll can never complete -> CAPP break stages garbage -> divergence.
// R5: lock-in polls (capture each u64 the moment its tag matches) with
// HOISTED unconditional loads (4 back-to-back, checks after -> one L3 round
// trip per round), ring depth 256 (fallback 128), back-pressure every 8
// steps @ t-48, poll CAPP x4. Protocol otherwise unchanged:
// ring u32 = (tag=t+1)<<16 | f16(state); tags self-validate; stale replay
// tags never match (slots rewritten with small tags before large polls).

#define R_    2048
#define I_    32
#define O_    32
#define NSTEP 8191
#define G_    128
#define GR_   32
#define BLK   256
#define CAPP  (1u << 24)   // data-poll cap: fail loud, never hang
#define CAPB  (1u << 22)   // back-pressure cap (blocking is the safe direction)

typedef unsigned int u32;
typedef unsigned long long u64;

__device__ __forceinline__ float tanh_fast(float u) {
    float e = __expf(2.f * u);            // inf-safe: overflow -> +/-1 exactly
    return 1.f - __fdividef(2.f, e + 1.f);
}

__device__ __forceinline__ u32 pkh(float v, u32 tag) {
    return (tag << 16) | (u32)__half_as_ushort(__float2half(v));
}

__device__ __forceinline__ u64 ald(const u64* p) {
    return __hip_atomic_load(p, __ATOMIC_RELAXED, __HIP_MEMORY_SCOPE_AGENT);
}

// ws layout: [0,128) rprog[32] ; [4096, 4096 + DSLOT*R_*4) ring u32[DSLOT][R_]

__global__ __launch_bounds__(256) void esn_init(const float* __restrict__ X,
                                                const float* __restrict__ W_out,
                                                float* __restrict__ out,
                                                int* __restrict__ rprog)
{
    int idx = blockIdx.x * blockDim.x + threadIdx.x;
    if (idx < GR_)
        __hip_atomic_store(&rprog[idx], 0, __ATOMIC_RELAXED,
                           __HIP_MEMORY_SCOPE_AGENT);
    if (idx < NSTEP * O_) {
        int q = idx >> 5;
        int o = idx & 31;
        const float* wrow = W_out + o * (R_ + I_) + R_;
        const float* xrow = X + q * I_;
        float acc = 0.f;
        #pragma unroll
        for (int j = 0; j < I_; ++j) acc = fmaf(wrow[j], xrow[j], acc);
        out[idx] = acc;
    }
}

__global__ __launch_bounds__(BLK, 1) void esn_main(
    const float* __restrict__ X, const float* __restrict__ W_in,
    const float* __restrict__ W_res, const float* __restrict__ W_out,
    const float* __restrict__ state0, float* __restrict__ out,
    u32* __restrict__ ring, int* __restrict__ rprog, int dmask)
{
    const int tid = threadIdx.x;
    const int g   = blockIdx.x;
    __shared__ float s_lds[2][R_];

    if (g < G_) {
        // ---------------- producer: rows [g*16, g*16+16) ----------------
        const int lane  = tid & 63;
        const int wave  = tid >> 6;
        const int myrow = g * 16 + wave * 4;    // this wave's 4 rows

        float4 w[4][8];
        #pragma unroll
        for (int i = 0; i < 4; ++i) {
            const float* wr = W_res + (size_t)(myrow + i) * R_;
            #pragma unroll
            for (int k = 0; k < 8; ++k)
                w[i][k] = *reinterpret_cast<const float4*>(wr + k * 256 + 4 * lane);
        }
        float wi[4];
        #pragma unroll
        for (int i = 0; i < 4; ++i)
            wi[i] = (lane < 32) ? W_in[(size_t)(myrow + i) * I_ + lane] : 0.f;

        // pin weights in VGPRs (asm outputs can't be rematerialized as loads)
        #pragma unroll
        for (int i = 0; i < 4; ++i) {
            #pragma unroll
            for (int k = 0; k < 8; ++k)
                asm volatile("" : "+v"(w[i][k].x), "+v"(w[i][k].y),
                                  "+v"(w[i][k].z), "+v"(w[i][k].w));
            asm volatile("" : "+v"(wi[i]));
        }

        // seed s_0 into buffer 0
        #pragma unroll
        for (int q = 0; q < 8; ++q)
            s_lds[0][q * 256 + tid] = state0[q * 256 + tid];
        __syncthreads();

        float xl = (lane < 32) ? X[lane] : 0.f;

        for (int t = 0; t < NSTEP; ++t) {
            // sampled back-pressure before this step's overwriting store.
            // margin: producers pass only while rprog >= t-48; overshoot
            // <= 8 (sample) + 1 (lockstep); destroyed tags <= t+10-dslot;
            // reader pending tag >= t-48+33 -> >100-tag margin at dslot=128.
            if ((t & 7) == 0 && t > dmask) {
                unsigned tries = 0;
                while (__hip_atomic_load(&rprog[g & (GR_ - 1)], __ATOMIC_RELAXED,
                                         __HIP_MEMORY_SCOPE_AGENT) < t - 48) {
                    if (++tries > CAPB) break;
                    __builtin_amdgcn_s_sleep(16);
                }
            }

            const float* sbuf = s_lds[t & 1];
            float p0 = wi[0] * xl, p1 = wi[1] * xl, p2 = wi[2] * xl, p3 = wi[3] * xl;
            #pragma unroll
            for (int k = 0; k < 8; ++k) {
                const float4 sv = *reinterpret_cast<const float4*>(
                    &sbuf[k * 256 + 4 * lane]);
                p0 = fmaf(w[0][k].x, sv.x, p0); p0 = fmaf(w[0][k].y, sv.y, p0);
                p0 = fmaf(w[0][k].z, sv.z, p0); p0 = fmaf(w[0][k].w, sv.w, p0);
                p1 = fmaf(w[1][k].x, sv.x, p1); p1 = fmaf(w[1][k].y, sv.y, p1);
                p1 = fmaf(w[1][k].z, sv.z, p1); p1 = fmaf(w[1][k].w, sv.w, p1);
                p2 = fmaf(w[2][k].x, sv.x, p2); p2 = fmaf(w[2][k].y, sv.y, p2);
                p2 = fmaf(w[2][k].z, sv.z, p2); p2 = fmaf(w[2][k].w, sv.w, p2);
                p3 = fmaf(w[3][k].x, sv.x, p3); p3 = fmaf(w[3][k].y, sv.y, p3);
                p3 = fmaf(w[3][k].z, sv.z, p3); p3 = fmaf(w[3][k].w, sv.w, p3);
            }
            #pragma unroll
            for (int off = 1; off < 64; off <<= 1) {
                p0 += __shfl_xor(p0, off, 64);
                p1 += __shfl_xor(p1, off, 64);
                p2 += __shfl_xor(p2, off, 64);
                p3 += __shfl_xor(p3, off, 64);
            }
            // publish: all lanes hold all 4 sums; lane 0 packs + 2 u64 stores
            {
                const u32 tg = (u32)(t + 1);
                float v0 = tanh_fast(p0), v1 = tanh_fast(p1);
                float v2 = tanh_fast(p2), v3 = tanh_fast(p3);
                if (lane == 0) {
                    u64* dst = (u64*)(ring + (size_t)((t + 1) & dmask) * R_ + myrow);
                    u64 q0 = (u64)pkh(v0, tg) | ((u64)pkh(v1, tg) << 32);
                    u64 q1 = (u64)pkh(v2, tg) | ((u64)pkh(v3, tg) << 32);
                    __hip_atomic_store(&dst[0], q0, __ATOMIC_RELAXED,
                                       __HIP_MEMORY_SCOPE_AGENT);
                    __hip_atomic_store(&dst[1], q1, __ATOMIC_RELAXED,
                                       __HIP_MEMORY_SCOPE_AGENT);
                }
            }
            if (t == NSTEP - 1) break;

            float xn = (lane < 32) ? X[(size_t)(t + 1) * I_ + lane] : 0.f;

            // poll slot t+1: hoisted unconditional loads + per-u64 LOCK-IN
            u64 a0 = 0, a1 = 0, a2 = 0, a3 = 0;
            {
                const u32 tg  = (u32)(t + 1);
                const u64 pat = ((u64)tg << 48) | ((u64)tg << 16);
                const u64 msk = 0xFFFF0000FFFF0000ull;
                const u64* p64 = (const u64*)(ring + (size_t)((t + 1) & dmask) * R_);
                unsigned pend = 0xFu, tries = 0;
                for (;;) {
                    u64 b0 = ald(&p64[0 * 256 + tid]);
                    u64 b1 = ald(&p64[1 * 256 + tid]);
                    u64 b2 = ald(&p64[2 * 256 + tid]);
                    u64 b3 = ald(&p64[3 * 256 + tid]);
                    if ((pend & 1u) && !((b0 ^ pat) & msk)) { a0 = b0; pend &= ~1u; }
                    if ((pend & 2u) && !((b1 ^ pat) & msk)) { a1 = b1; pend &= ~2u; }
                    if ((pend & 4u) && !((b2 ^ pat) & msk)) { a2 = b2; pend &= ~4u; }
                    if ((pend & 8u) && !((b3 ^ pat) & msk)) { a3 = b3; pend &= ~8u; }
                    if (!pend) break;
                    if (++tries > CAPP) break;   // fail loud, never hang
                    __builtin_amdgcn_s_sleep(1);
                }
            }
            // stage into the other buffer
            {
                float* dbuf = s_lds[(t + 1) & 1];
                float2 f;
                f.x = __half2float(__ushort_as_half((unsigned short)a0));
                f.y = __half2float(__ushort_as_half((unsigned short)(a0 >> 32)));
                *reinterpret_cast<float2*>(&dbuf[0 * 512 + 2 * tid]) = f;
                f.x = __half2float(__ushort_as_half((unsigned short)a1));
                f.y = __half2float(__ushort_as_half((unsigned short)(a1 >> 32)));
                *reinterpret_cast<float2*>(&dbuf[1 * 512 + 2 * tid]) = f;
                f.x = __half2float(__ushort_as_half((unsigned short)a2));
                f.y = __half2float(__ushort_as_half((unsigned short)(a2 >> 32)));
                *reinterpret_cast<float2*>(&dbuf[2 * 512 + 2 * tid]) = f;
                f.x = __half2float(__ushort_as_half((unsigned short)a3));
                f.y = __half2float(__ushort_as_half((unsigned short)(a3 >> 32)));
                *reinterpret_cast<float2*>(&dbuf[3 * 512 + 2 * tid]) = f;
            }
            xl = xn;
            __syncthreads();   // stage complete; dbuf + 1 barrier is safe
        }
    } else {
        // ---------------- reader: steps t === r (mod 32) ----------------
        const int r = g - G_;
        const int o = tid >> 3;            // output 0..31
        const int c = tid & 7;             // col-chunk (256 cols)
        const float* wrow = W_out + (size_t)o * (R_ + I_) + c * 256;

        for (int t = r; t < NSTEP; t += GR_) {
            const u32 tg  = (u32)(t + 1);
            const u64 pat = ((u64)tg << 48) | ((u64)tg << 16);
            const u64 msk = 0xFFFF0000FFFF0000ull;
            const u64* p64 = (const u64*)(ring + (size_t)((t + 1) & dmask) * R_);
            u64 a0 = 0, a1 = 0, a2 = 0, a3 = 0;
            unsigned pend = 0xFu, tries = 0;
            for (;;) {
                u64 b0 = ald(&p64[0 * 256 + tid]);
                u64 b1 = ald(&p64[1 * 256 + tid]);
                u64 b2 = ald(&p64[2 * 256 + tid]);
                u64 b3 = ald(&p64[3 * 256 + tid]);
                if ((pend & 1u) && !((b0 ^ pat) & msk)) { a0 = b0; pend &= ~1u; }
                if ((pend & 2u) && !((b1 ^ pat) & msk)) { a1 = b1; pend &= ~2u; }
                if ((pend & 4u) && !((b2 ^ pat) & msk)) { a2 = b2; pend &= ~4u; }
                if ((pend & 8u) && !((b3 ^ pat) & msk)) { a3 = b3; pend &= ~8u; }
                if (!pend) break;
                if (++tries > CAPP) break;
                __builtin_amdgcn_s_sleep(2);
            }
            float2 f;
            f.x = __half2float(__ushort_as_half((unsigned short)a0));
            f.y = __half2float(__ushort_as_half((unsigned short)(a0 >> 32)));
            *reinterpret_cast<float2*>(&s_lds[0][0 * 512 + 2 * tid]) = f;
            f.x = __half2float(__ushort_as_half((unsigned short)a1));
            f.y = __half2float(__ushort_as_half((unsigned short)(a1 >> 32)));
            *reinterpret_cast<float2*>(&s_lds[0][1 * 512 + 2 * tid]) = f;
            f.x = __half2float(__ushort_as_half((unsigned short)a2));
            f.y = __half2float(__ushort_as_half((unsigned short)(a2 >> 32)));
            *reinterpret_cast<float2*>(&s_lds[0][2 * 512 + 2 * tid]) = f;
            f.x = __half2float(__ushort_as_half((unsigned short)a3));
            f.y = __half2float(__ushort_as_half((unsigned short)(a3 >> 32)));
            *reinterpret_cast<float2*>(&s_lds[0][3 * 512 + 2 * tid]) = f;
            __syncthreads();
            if (tid == 0)
                __hip_atomic_store(&rprog[r], t, __ATOMIC_RELAXED,
                                   __HIP_MEMORY_SCOPE_AGENT);

            float acc = 0.f;
            #pragma unroll 16
            for (int j = 0; j < 256; j += 4) {
                float4 wv = *reinterpret_cast<const float4*>(wrow + j);
                float4 sv = *reinterpret_cast<const float4*>(&s_lds[0][c * 256 + j]);
                acc = fmaf(wv.x, sv.x, acc);
                acc = fmaf(wv.y, sv.y, acc);
                acc = fmaf(wv.z, sv.z, acc);
                acc = fmaf(wv.w, sv.w, acc);
            }
            acc += __shfl_xor(acc, 1, 64);
            acc += __shfl_xor(acc, 2, 64);
            acc += __shfl_xor(acc, 4, 64);
            if (c == 0) out[t * O_ + o] += acc;   // exclusive writer
            __syncthreads();                      // protect s_lds before restage
        }
    }
}

extern "C" void kernel_launch(void* const* d_in, const int* in_sizes, int n_in,
                              void* d_out, int out_size, void* d_ws, size_t ws_size,
                              hipStream_t stream)
{
    (void)in_sizes; (void)n_in; (void)out_size;
    const float* X      = (const float*)d_in[0];
    const float* W_in   = (const float*)d_in[1];
    const float* W_res  = (const float*)d_in[2];
    const float* W_out  = (const float*)d_in[3];
    const float* state0 = (const float*)d_in[4];
    float* out = (float*)d_out;

    char* ws    = (char*)d_ws;
    int*  rprog = (int*)ws;
    u32*  ring  = (u32*)(ws + 4096);

    // ring depth: 256 slots (2 MiB) if workspace allows, else 128 (1 MiB)
    int dmask = (ws_size >= 4096 + (size_t)256 * R_ * 4) ? 255 : 127;

    hipLaunchKernelGGL(esn_init, dim3(1024), dim3(256), 0, stream,
                       X, W_out, out, rprog);
    hipLaunchKernelGGL(esn_main, dim3(G_ + GR_), dim3(BLK), 0, stream,
                       X, W_in, W_res, W_out, state0, out, ring, rprog, dmask);
}